// Round 10
// baseline (245.824 us; speedup 1.0000x reference)
//
#include <hip/hip_runtime.h>
#include <math.h>

// ============================================================================
// ROUND 10 = DIAGNOSTIC ROUND. Kernels are byte-identical to R7 (best, 172.5).
// k_winsum is launched TWICE (idempotent). The end-to-end delta vs R7
// isolates winsum's duration, splitting the winsum/fuse attribution that the
// rocprof top-5 (all harness fills) hides. Next round reverts to single
// launch and uses the number.
// ============================================================================

// Problem constants (from reference setup_inputs)
constexpr int B = 2, S = 5, C = 256, H = 200, W = 200;
constexpr int KW = 7;              // window
constexpr int HB = 29, WB = 29;    // ceil(203/7)
constexpr int HID = 16;
constexpr int NW = HB * WB;        // 841

// ---------------------------------------------------------------------------
// Kernel 1: per-window channel sums, one 512-thread block per (b,s,c) plane.
// Phase A: thread owns (hb, x4): 7 vertically-adjacent float4 loads summed
// into LDS colg[29][200]. ONE barrier. Phase B: horizontal 7-window sums ->
// gsum (contiguous). gsum layout: [B*S*C][841]
// ---------------------------------------------------------------------------
__global__ __launch_bounds__(512) void k_winsum(const float* __restrict__ feats,
                                                float* __restrict__ gsum) {
    const int blk = (int)blockIdx.x;            // (b*S+s)*C + c
    const float* src = feats + (size_t)blk * (H * W);

    __shared__ float colg[HB * W];              // 23.2 KB

    const int tid = (int)threadIdx.x;

    // Phase A: 29*50 = 1450 items
    for (int q = tid; q < HB * (W / 4); q += 512) {
        int hb = q / (W / 4);
        int x4 = q - hb * (W / 4);
        int y0 = hb * KW;
        float4 a = make_float4(0.f, 0.f, 0.f, 0.f);
#pragma unroll
        for (int i = 0; i < KW; ++i) {
            int y = y0 + i;
            if (y < H) {
                float4 v = ((const float4*)(src + (size_t)y * W))[x4];
                a.x += v.x; a.y += v.y; a.z += v.z; a.w += v.w;
            }
        }
        ((float4*)(colg + hb * W))[x4] = a;
    }
    __syncthreads();

    // Phase B: 841 horizontal window sums, contiguous store
    float* dst = gsum + (size_t)blk * NW;
    for (int p = tid; p < NW; p += 512) {
        int hb = p / WB;
        int wb = p - hb * WB;
        int x0 = wb * KW;
        float s = 0.f;
#pragma unroll
        for (int j = 0; j < KW; ++j) {
            int x = x0 + j;
            if (x < W) s += colg[hb * W + x];
        }
        dst[p] = s;
    }
}

// ---------------------------------------------------------------------------
// Kernel 2: MLP + softmax over wb. One 256-thread block per (b,s,hb).
// ---------------------------------------------------------------------------
__global__ __launch_bounds__(256) void k_weights(const float* __restrict__ gsum,
                                                 const float* __restrict__ w1,
                                                 const float* __restrict__ b1,
                                                 const float* __restrict__ w2,
                                                 const float* __restrict__ b2,
                                                 float* __restrict__ weights) {
    int blk = blockIdx.x;
    int hb = blk % HB; blk /= HB;
    int s  = blk % S;
    int b  = blk / S;
    const int bs = b * S + s;

    __shared__ float w1s[HID * C];        // 16 KB
    __shared__ float part[8 * HID * WB];  // 14.5 KB
    __shared__ float lg[WB];

    const int tid = (int)threadIdx.x;
    for (int i = tid; i < HID * C; i += 256) w1s[i] = w1[i];
    __syncthreads();

    if (tid < 8 * WB) {                   // 232 active
        const int cg = tid / WB;          // 0..7
        const int wb = tid - cg * WB;     // 0..28
        float acc[HID];
#pragma unroll
        for (int d = 0; d < HID; ++d) acc[d] = 0.f;
        const float* g = gsum + (size_t)bs * C * NW + hb * WB + wb;
        const int c0 = cg * (C / 8);
#pragma unroll 4
        for (int c = c0; c < c0 + C / 8; ++c) {
            float gc = g[(size_t)c * NW];
#pragma unroll
            for (int d = 0; d < HID; ++d) acc[d] += gc * w1s[d * C + c];
        }
#pragma unroll
        for (int d = 0; d < HID; ++d) part[(cg * HID + d) * WB + wb] = acc[d];
    }
    __syncthreads();

    if (tid < WB) {
        float logit = b2[0];
#pragma unroll
        for (int d = 0; d < HID; ++d) {
            float a = 0.f;
#pragma unroll
            for (int cg = 0; cg < 8; ++cg) a += part[(cg * HID + d) * WB + tid];
            float h = a * (1.0f / 49.0f) + b1[d];
            logit += fmaxf(h, 0.0f) * w2[d];
        }
        lg[tid] = logit;
    }
    __syncthreads();
    if (tid < WB) {
        float m = -INFINITY;
        for (int t = 0; t < WB; ++t) m = fmaxf(m, lg[t]);
        float sum = 0.f;
        for (int t = 0; t < WB; ++t) sum += expf(lg[t] - m);
        weights[(size_t)bs * NW + hb * WB + tid] = expf(lg[tid] - m) / sum;
    }
}

// ---------------------------------------------------------------------------
// Kernel 3 (band-structured, R7): block = (b, c, hb). The 7 output rows
// {y = i*29+hb} consume exactly the 7 CONTIGUOUS input rows hb*7..hb*7+6
// and share ONE weight row per slice. 512 threads, 28.6 KB LDS.
// ---------------------------------------------------------------------------
__global__ __launch_bounds__(512) void k_fuse(const float* __restrict__ feats,
                                              const float* __restrict__ weights,
                                              float* __restrict__ out) {
    int blk = blockIdx.x;
    const int hb = blk % HB; blk /= HB;
    const int c  = (C - 1) - (blk % C);
    const int b  = (B - 1) - (blk / C);

    __shared__ float buf[S][KW * W];     // 28 KB
    __shared__ float wsl[S][WB];         // 580 B

    const int tid = (int)threadIdx.x;
    const size_t plane = (size_t)H * W;
    const size_t sstride = (size_t)C * plane;
    const float* f0 = feats + ((size_t)b * S * C + c) * plane;
    const int y_in0 = hb * KW;

    for (int q = tid; q < S * 350; q += 512) {
        int s = q / 350;
        int r = q - s * 350;
        int i = r / 50;
        float4 v = make_float4(0.f, 0.f, 0.f, 0.f);
        if (y_in0 + i < H)
            v = ((const float4*)(f0 + (size_t)s * sstride + (size_t)y_in0 * W))[r];
        ((float4*)&buf[s][0])[r] = v;
    }
    if (tid < S * WB) {
        int s  = tid / WB;
        int wb = tid - s * WB;
        wsl[s][wb] = weights[((size_t)((b * S + s) * HB + hb)) * WB + wb];
    }
    __syncthreads();

    float* o = out + ((size_t)b * C + c) * plane;
    for (int p = tid; p < KW * 50; p += 512) {
        int i = p / 50;
        int y = i * HB + hb;
        if (y < H) {
            int x0 = (p - i * 50) * 4;
            float4 r4;
            float* rp = (float*)&r4;
#pragma unroll
            for (int u = 0; u < 4; ++u) {
                int x  = x0 + u;
                int j  = x / WB;
                int wb = x - j * WB;
                int x_in = wb * KW + j;
                float acc = 0.f;
                if (x_in < W) {
#pragma unroll
                    for (int s = 0; s < S; ++s)
                        acc += buf[s][i * W + x_in] * wsl[s][wb];
                }
                rp[u] = acc;
            }
            ((float4*)(o + (size_t)y * W))[x0 / 4] = r4;
        }
    }
}

// ---------------------------------------------------------------------------
extern "C" void kernel_launch(void* const* d_in, const int* in_sizes, int n_in,
                              void* d_out, int out_size, void* d_ws, size_t ws_size,
                              hipStream_t stream) {
    const float* feats = (const float*)d_in[0];
    const float* w1    = (const float*)d_in[1];
    const float* b1    = (const float*)d_in[2];
    const float* w2    = (const float*)d_in[3];
    const float* b2    = (const float*)d_in[4];
    float* out = (float*)d_out;

    // Workspace layout
    float* gsum    = (float*)d_ws;                      // B*S*C*841 floats
    float* weights = gsum + (size_t)B * S * C * NW;     // B*S*841 floats

    // DIAGNOSTIC: winsum launched twice (idempotent — rewrites identical
    // values). Delta vs R7's 172.5 us isolates winsum's duration.
    hipLaunchKernelGGL(k_winsum, dim3(B * S * C), dim3(512), 0, stream, feats, gsum);
    hipLaunchKernelGGL(k_winsum, dim3(B * S * C), dim3(512), 0, stream, feats, gsum);
    // Kernel 2: MLP + softmax -> weights
    hipLaunchKernelGGL(k_weights, dim3(B * S * HB), dim3(256), 0, stream,
                       gsum, w1, b1, w2, b2, weights);
    // Kernel 3: band-structured weighted fusion (R7)
    hipLaunchKernelGGL(k_fuse, dim3(B * C * HB), dim3(512), 0, stream,
                       feats, weights, out);
}

// Round 11
// 171.828 us; speedup vs baseline: 1.4306x; 1.4306x over previous
//
#include <hip/hip_runtime.h>
#include <math.h>

// Problem constants (from reference setup_inputs)
constexpr int B = 2, S = 5, C = 256, H = 200, W = 200;
constexpr int KW = 7;              // window
constexpr int HB = 29, WB = 29;    // ceil(203/7)
constexpr int HID = 16;
constexpr int NW = HB * WB;        // 841

// ---------------------------------------------------------------------------
// Kernel 1: per-window channel sums, one 512-thread block per (b,s,c) plane.
// Phase A restructured (R11): each thread owns its 3 item-slots explicitly;
// all 21 global float4 loads are issued as independent register streams
// (no per-iteration LDS write forcing vmcnt drains), then 3 ds_writes.
// Phase B: horizontal 7-window sums -> gsum (contiguous). [B*S*C][841]
// ---------------------------------------------------------------------------
__global__ __launch_bounds__(512) void k_winsum(const float* __restrict__ feats,
                                                float* __restrict__ gsum) {
    const int blk = (int)blockIdx.x;            // (b*S+s)*C + c
    const float* src = feats + (size_t)blk * (H * W);

    __shared__ float colg[HB * W];              // 23.2 KB

    const int tid = (int)threadIdx.x;

    // Phase A: 1450 items in 3 slots/thread, loads fully front-issued
    float4 a[3];
    int hbv[3], x4v[3];
    bool act[3];
#pragma unroll
    for (int k = 0; k < 3; ++k) {
        int q = tid + k * 512;
        act[k] = q < HB * (W / 4);
        hbv[k] = q / (W / 4);
        x4v[k] = q - hbv[k] * (W / 4);
        a[k] = make_float4(0.f, 0.f, 0.f, 0.f);
    }
#pragma unroll
    for (int i = 0; i < KW; ++i) {
#pragma unroll
        for (int k = 0; k < 3; ++k) {
            if (act[k]) {
                int y = hbv[k] * KW + i;
                if (y < H) {
                    float4 v = ((const float4*)(src + (size_t)y * W))[x4v[k]];
                    a[k].x += v.x; a[k].y += v.y; a[k].z += v.z; a[k].w += v.w;
                }
            }
        }
    }
#pragma unroll
    for (int k = 0; k < 3; ++k)
        if (act[k]) ((float4*)(colg + hbv[k] * W))[x4v[k]] = a[k];
    __syncthreads();

    // Phase B: 841 horizontal window sums, contiguous store
    float* dst = gsum + (size_t)blk * NW;
    for (int p = tid; p < NW; p += 512) {
        int hb = p / WB;
        int wb = p - hb * WB;
        int x0 = wb * KW;
        float s = 0.f;
#pragma unroll
        for (int j = 0; j < KW; ++j) {
            int x = x0 + j;
            if (x < W) s += colg[hb * W + x];
        }
        dst[p] = s;
    }
}

// ---------------------------------------------------------------------------
// Kernel 2: MLP + softmax over wb. One 256-thread block per (b,s,hb).
// ---------------------------------------------------------------------------
__global__ __launch_bounds__(256) void k_weights(const float* __restrict__ gsum,
                                                 const float* __restrict__ w1,
                                                 const float* __restrict__ b1,
                                                 const float* __restrict__ w2,
                                                 const float* __restrict__ b2,
                                                 float* __restrict__ weights) {
    int blk = blockIdx.x;
    int hb = blk % HB; blk /= HB;
    int s  = blk % S;
    int b  = blk / S;
    const int bs = b * S + s;

    __shared__ float w1s[HID * C];        // 16 KB
    __shared__ float part[8 * HID * WB];  // 14.5 KB
    __shared__ float lg[WB];

    const int tid = (int)threadIdx.x;
    for (int i = tid; i < HID * C; i += 256) w1s[i] = w1[i];
    __syncthreads();

    if (tid < 8 * WB) {                   // 232 active
        const int cg = tid / WB;          // 0..7
        const int wb = tid - cg * WB;     // 0..28
        float acc[HID];
#pragma unroll
        for (int d = 0; d < HID; ++d) acc[d] = 0.f;
        const float* g = gsum + (size_t)bs * C * NW + hb * WB + wb;
        const int c0 = cg * (C / 8);
#pragma unroll 4
        for (int c = c0; c < c0 + C / 8; ++c) {
            float gc = g[(size_t)c * NW];
#pragma unroll
            for (int d = 0; d < HID; ++d) acc[d] += gc * w1s[d * C + c];
        }
#pragma unroll
        for (int d = 0; d < HID; ++d) part[(cg * HID + d) * WB + wb] = acc[d];
    }
    __syncthreads();

    if (tid < WB) {
        float logit = b2[0];
#pragma unroll
        for (int d = 0; d < HID; ++d) {
            float a = 0.f;
#pragma unroll
            for (int cg = 0; cg < 8; ++cg) a += part[(cg * HID + d) * WB + tid];
            float h = a * (1.0f / 49.0f) + b1[d];
            logit += fmaxf(h, 0.0f) * w2[d];
        }
        lg[tid] = logit;
    }
    __syncthreads();
    if (tid < WB) {
        float m = -INFINITY;
        for (int t = 0; t < WB; ++t) m = fmaxf(m, lg[t]);
        float sum = 0.f;
        for (int t = 0; t < WB; ++t) sum += expf(lg[t] - m);
        weights[(size_t)bs * NW + hb * WB + tid] = expf(lg[tid] - m) / sum;
    }
}

// ---------------------------------------------------------------------------
// Kernel 3 (band-structured, R7 + R11 staging): block = (b, c, hb). The 7
// output rows {y = i*29+hb} consume exactly the 7 CONTIGUOUS input rows
// hb*7..hb*7+6 and share ONE weight row per slice. Staging loads issued as
// 4 independent register slots before any LDS write (no per-slot vmcnt
// drain). 512 threads, 28.6 KB LDS.
// ---------------------------------------------------------------------------
__global__ __launch_bounds__(512) void k_fuse(const float* __restrict__ feats,
                                              const float* __restrict__ weights,
                                              float* __restrict__ out) {
    int blk = blockIdx.x;
    const int hb = blk % HB; blk /= HB;
    const int c  = (C - 1) - (blk % C);
    const int b  = (B - 1) - (blk / C);

    __shared__ float buf[S][KW * W];     // 28 KB
    __shared__ float wsl[S][WB];         // 580 B

    const int tid = (int)threadIdx.x;
    const size_t plane = (size_t)H * W;
    const size_t sstride = (size_t)C * plane;
    const float* f0 = feats + ((size_t)b * S * C + c) * plane;
    const int y_in0 = hb * KW;

    // stage: 1750 float4 items in 4 slots/thread, loads front-issued
    {
        float4 v[4];
        int sv[4], rv[4];
        bool act[4];
#pragma unroll
        for (int k = 0; k < 4; ++k) {
            int q = tid + k * 512;
            act[k] = q < S * 350;
            sv[k] = q / 350;
            rv[k] = q - sv[k] * 350;
            v[k] = make_float4(0.f, 0.f, 0.f, 0.f);
            if (act[k]) {
                int i = rv[k] / 50;
                if (y_in0 + i < H)
                    v[k] = ((const float4*)(f0 + (size_t)sv[k] * sstride +
                                            (size_t)y_in0 * W))[rv[k]];
            }
        }
#pragma unroll
        for (int k = 0; k < 4; ++k)
            if (act[k]) ((float4*)&buf[sv[k]][0])[rv[k]] = v[k];
    }
    if (tid < S * WB) {
        int s  = tid / WB;
        int wb = tid - s * WB;
        wsl[s][wb] = weights[((size_t)((b * S + s) * HB + hb)) * WB + wb];
    }
    __syncthreads();

    float* o = out + ((size_t)b * C + c) * plane;
    for (int p = tid; p < KW * 50; p += 512) {
        int i = p / 50;
        int y = i * HB + hb;
        if (y < H) {
            int x0 = (p - i * 50) * 4;
            float4 r4;
            float* rp = (float*)&r4;
#pragma unroll
            for (int u = 0; u < 4; ++u) {
                int x  = x0 + u;
                int j  = x / WB;
                int wb = x - j * WB;
                int x_in = wb * KW + j;
                float acc = 0.f;
                if (x_in < W) {
#pragma unroll
                    for (int s = 0; s < S; ++s)
                        acc += buf[s][i * W + x_in] * wsl[s][wb];
                }
                rp[u] = acc;
            }
            ((float4*)(o + (size_t)y * W))[x0 / 4] = r4;
        }
    }
}

// ---------------------------------------------------------------------------
extern "C" void kernel_launch(void* const* d_in, const int* in_sizes, int n_in,
                              void* d_out, int out_size, void* d_ws, size_t ws_size,
                              hipStream_t stream) {
    const float* feats = (const float*)d_in[0];
    const float* w1    = (const float*)d_in[1];
    const float* b1    = (const float*)d_in[2];
    const float* w2    = (const float*)d_in[3];
    const float* b2    = (const float*)d_in[4];
    float* out = (float*)d_out;

    // Workspace layout
    float* gsum    = (float*)d_ws;                      // B*S*C*841 floats
    float* weights = gsum + (size_t)B * S * C * NW;     // B*S*841 floats

    // Kernel 1: window sums (one 512-thread block per plane)
    hipLaunchKernelGGL(k_winsum, dim3(B * S * C), dim3(512), 0, stream, feats, gsum);
    // Kernel 2: MLP + softmax -> weights
    hipLaunchKernelGGL(k_weights, dim3(B * S * HB), dim3(256), 0, stream,
                       gsum, w1, b1, w2, b2, weights);
    // Kernel 3: band-structured weighted fusion
    hipLaunchKernelGGL(k_fuse, dim3(B * C * HB), dim3(512), 0, stream,
                       feats, weights, out);
}